// Round 2
// baseline (623.733 us; speedup 1.0000x reference)
//
#include <hip/hip_runtime.h>
#include <hip/hip_bf16.h>

typedef short bh8 __attribute__((ext_vector_type(8)));
typedef float f32x4 __attribute__((ext_vector_type(4)));

#define NBLOCKS 256
#define NWAVES_TOTAL (NBLOCKS * 8)

__device__ __forceinline__ short f2bf(float f) {
  __hip_bfloat16 h = __float2bfloat16(f);   // HW RNE cvt (v_cvt_pk_bf16_f32 when paired)
  return *reinterpret_cast<short*>(&h);
}

struct alignas(16) SMem {
  // A-operand (W^T) fragments, frag-linearized: [out_block][k_block][lane][8 bf16]
  // lane l holds rows ob*16+(l&15); elems 0-3: k=kb*32+(l>>4)*4+i, elems 4-7: k=kb*32+16+(l>>4)*4+(i-4)
  ushort w1[8][8][64][8];   // 65536 B  (K=256 part of W1)
  ushort w2[8][4][64][8];   // 32768 B
  ushort w3[8][4][64][8];   // 32768 B
  float b1[128]; float b2[128]; float b3[128];
  float w4[128]; float w1g[128];   // w1g = W1[256][:] (graph-scalar row)
};

template<int WITH_G>
__device__ __forceinline__ void relu_pack(f32x4 (&acc)[4][8], bh8 (&bp)[4][4],
                                          const float* bias, const float* w1g,
                                          const float (&gv)[4], int q) {
#pragma unroll
  for (int et = 0; et < 4; ++et) {
#pragma unroll
    for (int kf = 0; kf < 4; ++kf) {
      bh8 t;
#pragma unroll
      for (int half = 0; half < 2; ++half) {
        int ob = kf * 2 + half;
#pragma unroll
        for (int r = 0; r < 4; ++r) {
          int f = ob * 16 + q * 4 + r;
          float v = acc[et][ob][r] + bias[f];
          if (WITH_G) v += gv[et] * w1g[f];
          v = fmaxf(v, 0.0f);
          t[half * 4 + r] = f2bf(v);
        }
      }
      bp[et][kf] = t;
    }
  }
}

__global__ __launch_bounds__(512, 2) void edge_mlp(
    const float* __restrict__ z, const float* __restrict__ graph,
    const int* __restrict__ ei,
    const float* __restrict__ W1, const float* __restrict__ b1,
    const float* __restrict__ W2, const float* __restrict__ b2,
    const float* __restrict__ W3, const float* __restrict__ b3,
    const float* __restrict__ W4, const float* __restrict__ b4,
    float* __restrict__ out, int E, int NN) {
  __shared__ SMem s;
  const int tid = threadIdx.x;

  // ---- stage weights (once per persistent block) ----
  for (int idx = tid; idx < 8 * 8 * 64 * 8; idx += 512) {
    int e = idx & 7, l = (idx >> 3) & 63, kb = (idx >> 9) & 7, ob = idx >> 12;
    int q = l >> 4;
    int k = kb * 32 + (e < 4 ? q * 4 + e : 16 + q * 4 + (e - 4));
    int n = ob * 16 + (l & 15);
    s.w1[ob][kb][l][e] = (ushort)f2bf(W1[k * 128 + n]);
  }
  for (int idx = tid; idx < 8 * 4 * 64 * 8; idx += 512) {
    int e = idx & 7, l = (idx >> 3) & 63, kb = (idx >> 9) & 3, ob = idx >> 11;
    int q = l >> 4;
    int k = kb * 32 + (e < 4 ? q * 4 + e : 16 + q * 4 + (e - 4));
    int n = ob * 16 + (l & 15);
    s.w2[ob][kb][l][e] = (ushort)f2bf(W2[k * 128 + n]);
    s.w3[ob][kb][l][e] = (ushort)f2bf(W3[k * 128 + n]);
  }
  if (tid < 128) {
    s.b1[tid] = b1[tid]; s.b2[tid] = b2[tid]; s.b3[tid] = b3[tid];
    s.w4[tid] = W4[tid]; s.w1g[tid] = W1[256 * 128 + tid];
  }
  __syncthreads();

  const float b4v = b4[0];
  const int lane = tid & 63;
  const int c = lane & 15;      // column within tile = edge-in-tile
  const int q = lane >> 4;
  const int wgid = (int)blockIdx.x * 8 + (tid >> 6);
  const int n_tiles = (E + 63) / 64;
  const f32x4 z4 = {0.f, 0.f, 0.f, 0.f};

  for (int tile = wgid; tile < n_tiles; tile += NWAVES_TOTAL) {
    const int ebase = tile * 64;

    int se[4], de[4];
    float gv[4];
#pragma unroll
    for (int et = 0; et < 4; ++et) {
      int e = ebase + et * 16 + c;
      if (e >= E) e = 0;
      se[et] = ei[e];
      de[et] = ei[E + e];
      gv[et] = graph[(long)se[et] * NN + de[et]];
    }

    // ---- layer 1: acc[f][edge] = sum_k W1^T[f][k] * feat[k][edge] ----
    f32x4 acc[4][8];
#pragma unroll
    for (int et = 0; et < 4; ++et)
#pragma unroll
      for (int ob = 0; ob < 8; ++ob) acc[et][ob] = z4;

#pragma unroll
    for (int kb = 0; kb < 8; ++kb) {
      bh8 bfr[4];
#pragma unroll
      for (int et = 0; et < 4; ++et) {
        const float* zr = z + (long)(kb < 4 ? se[et] : de[et]) * 128 + (kb & 3) * 32 + q * 4;
        float4 x = *(const float4*)zr;
        float4 y = *(const float4*)(zr + 16);
        bh8 t;
        t[0] = f2bf(x.x); t[1] = f2bf(x.y);
        t[2] = f2bf(x.z); t[3] = f2bf(x.w);
        t[4] = f2bf(y.x); t[5] = f2bf(y.y);
        t[6] = f2bf(y.z); t[7] = f2bf(y.w);
        bfr[et] = t;
      }
#pragma unroll
      for (int ob = 0; ob < 8; ++ob) {
        bh8 af = *(const bh8*)&s.w1[ob][kb][lane][0];
#pragma unroll
        for (int et = 0; et < 4; ++et)
          acc[et][ob] = __builtin_amdgcn_mfma_f32_16x16x32_bf16(af, bfr[et], acc[et][ob], 0, 0, 0);
      }
    }

    bh8 bp[4][4];
    relu_pack<1>(acc, bp, s.b1, s.w1g, gv, q);

    // ---- layer 2 ----
#pragma unroll
    for (int et = 0; et < 4; ++et)
#pragma unroll
      for (int ob = 0; ob < 8; ++ob) acc[et][ob] = z4;
#pragma unroll
    for (int kf = 0; kf < 4; ++kf) {
#pragma unroll
      for (int ob = 0; ob < 8; ++ob) {
        bh8 af = *(const bh8*)&s.w2[ob][kf][lane][0];
#pragma unroll
        for (int et = 0; et < 4; ++et)
          acc[et][ob] = __builtin_amdgcn_mfma_f32_16x16x32_bf16(af, bp[et][kf], acc[et][ob], 0, 0, 0);
      }
    }
    relu_pack<0>(acc, bp, s.b2, s.w1g, gv, q);

    // ---- layer 3 ----
#pragma unroll
    for (int et = 0; et < 4; ++et)
#pragma unroll
      for (int ob = 0; ob < 8; ++ob) acc[et][ob] = z4;
#pragma unroll
    for (int kf = 0; kf < 4; ++kf) {
#pragma unroll
      for (int ob = 0; ob < 8; ++ob) {
        bh8 af = *(const bh8*)&s.w3[ob][kf][lane][0];
#pragma unroll
        for (int et = 0; et < 4; ++et)
          acc[et][ob] = __builtin_amdgcn_mfma_f32_16x16x32_bf16(af, bp[et][kf], acc[et][ob], 0, 0, 0);
      }
    }

    // ---- layer 4 fused with layer-3 relu: value = sum_f relu(acc+b3)[f]*W4[f] ----
    float psum[4] = {0.f, 0.f, 0.f, 0.f};
#pragma unroll
    for (int et = 0; et < 4; ++et) {
#pragma unroll
      for (int ob = 0; ob < 8; ++ob) {
#pragma unroll
        for (int r = 0; r < 4; ++r) {
          int f = ob * 16 + q * 4 + r;
          float v = fmaxf(acc[et][ob][r] + s.b3[f], 0.0f);
          psum[et] += v * s.w4[f];
        }
      }
    }
#pragma unroll
    for (int et = 0; et < 4; ++et) {
      psum[et] += __shfl_xor(psum[et], 16, 64);
      psum[et] += __shfl_xor(psum[et], 32, 64);
    }
    float vsel = (q == 0) ? psum[0] : (q == 1) ? psum[1] : (q == 2) ? psum[2] : psum[3];
    float val = vsel + b4v;
    float sig = 1.0f / (1.0f + __expf(-val));
    int eout = ebase + q * 16 + c;
    if (eout < E) out[eout] = sig;
  }
}

extern "C" void kernel_launch(void* const* d_in, const int* in_sizes, int n_in,
                              void* d_out, int out_size, void* d_ws, size_t ws_size,
                              hipStream_t stream) {
  const float* z     = (const float*)d_in[0];
  // d_in[1] = scene_attr (unused by reference)
  const float* graph = (const float*)d_in[2];
  const int*   ei    = (const int*)d_in[3];
  const float* W1 = (const float*)d_in[4];
  const float* b1 = (const float*)d_in[5];
  const float* W2 = (const float*)d_in[6];
  const float* b2 = (const float*)d_in[7];
  const float* W3 = (const float*)d_in[8];
  const float* b3 = (const float*)d_in[9];
  const float* W4 = (const float*)d_in[10];
  const float* b4 = (const float*)d_in[11];
  int E  = in_sizes[3] / 2;
  int NN = in_sizes[0] / 128;
  hipLaunchKernelGGL(edge_mlp, dim3(NBLOCKS), dim3(512), 0, stream,
                     z, graph, ei, W1, b1, W2, b2, W3, b3, W4, b4,
                     (float*)d_out, E, NN);
}

// Round 3
// 313.567 us; speedup vs baseline: 1.9892x; 1.9892x over previous
//
#include <hip/hip_runtime.h>
#include <hip/hip_bf16.h>

typedef short bh8 __attribute__((ext_vector_type(8)));
typedef float f32x4 __attribute__((ext_vector_type(4)));

#define NBLOCKS 512
#define NWAVES_TOTAL (NBLOCKS * 8)

__device__ __forceinline__ short f2bf(float f) {
  __hip_bfloat16 h = __float2bfloat16(f);
  return *reinterpret_cast<short*>(&h);
}
__device__ __forceinline__ float bf2f(short s) {
  return __uint_as_float(((uint)(ushort)s) << 16);
}
// fragment permutation: feature f -> packed pos so one 16B load per (kf,q)
__device__ __forceinline__ int fpos(int f) {
  int kf = (f >> 5) & 3, h = (f >> 4) & 1, q = (f >> 2) & 3, j = f & 3;
  return (kf << 5) | (q << 3) | (h << 2) | j;
}

// ---- kernel 1: per-node Pa = z@W1a + b1, Pb = z@W1b, bf16 frag-permuted ----
__global__ __launch_bounds__(256) void precompute_p(
    const float* __restrict__ z, const float* __restrict__ W1,
    const float* __restrict__ b1, ushort* __restrict__ Pa,
    ushort* __restrict__ Pb, int NN) {
  __shared__ float zs[4][128];
  const int tid = threadIdx.x;
  const int n0 = blockIdx.x * 4;
  for (int i = tid; i < 512; i += 256) {
    int m = i >> 7, ff = i & 127, n = n0 + m;
    zs[m][ff] = (n < NN) ? z[n * 128 + ff] : 0.f;
  }
  __syncthreads();
  const int f = tid & 127;
  const bool isA = tid < 128;
  const float* w = W1 + (isA ? 0 : 128) * 128 + f;
  float a0, a1, a2, a3;
  a0 = a1 = a2 = a3 = isA ? b1[f] : 0.f;
#pragma unroll 16
  for (int k = 0; k < 128; ++k) {
    float wv = w[(size_t)k * 128];
    a0 += zs[0][k] * wv; a1 += zs[1][k] * wv;
    a2 += zs[2][k] * wv; a3 += zs[3][k] * wv;
  }
  ushort* dst = isA ? Pa : Pb;
  int pos = fpos(f);
  float av[4] = {a0, a1, a2, a3};
#pragma unroll
  for (int m = 0; m < 4; ++m)
    if (n0 + m < NN) dst[(size_t)(n0 + m) * 128 + pos] = (ushort)f2bf(av[m]);
}

// ---- kernel 2: pack W2/W3 into frag-linear bf16 ----
__global__ __launch_bounds__(512) void pack_w(
    const float* __restrict__ W2, const float* __restrict__ W3,
    ushort* __restrict__ w2f, ushort* __restrict__ w3f) {
  int idx = blockIdx.x * 512 + threadIdx.x;   // 32 blocks -> 16384
  if (idx >= 16384) return;
  int e = idx & 7, l = (idx >> 3) & 63, kb = (idx >> 9) & 3, ob = idx >> 11;
  int q = l >> 4;
  int k = kb * 32 + (e < 4 ? q * 4 + e : 16 + q * 4 + (e - 4));
  int n = ob * 16 + (l & 15);
  w2f[idx] = (ushort)f2bf(W2[k * 128 + n]);
  w3f[idx] = (ushort)f2bf(W3[k * 128 + n]);
}

// ---- kernel 3: main edge MLP (layers 2,3 MFMA; layer1 = gather-add) ----
struct alignas(16) SMem {
  ushort w2[16384];      // frag-linear: ((ob*4+kf)*64+lane)*8+e
  ushort w3[16384];
  float b2[128], b3[128], w4[128];
  ushort w1gp[128];      // W1[256][:] bf16, frag-permuted
};

__global__ __launch_bounds__(512, 2) void edge_mlp(
    const ushort* __restrict__ Pa, const ushort* __restrict__ Pb,
    const ushort* __restrict__ w2f, const ushort* __restrict__ w3f,
    const float* __restrict__ graph, const int* __restrict__ ei,
    const float* __restrict__ W1, const float* __restrict__ b2,
    const float* __restrict__ b3, const float* __restrict__ W4,
    const float* __restrict__ b4, float* __restrict__ out, int E, int NN) {
  __shared__ SMem s;
  const int tid = threadIdx.x;

  {
    const uint4* s2 = (const uint4*)w2f;
    const uint4* s3 = (const uint4*)w3f;
    uint4* d2 = (uint4*)s.w2;
    uint4* d3 = (uint4*)s.w3;
    for (int i = tid; i < 2048; i += 512) { d2[i] = s2[i]; d3[i] = s3[i]; }
    if (tid < 128) {
      s.b2[tid] = b2[tid]; s.b3[tid] = b3[tid]; s.w4[tid] = W4[tid];
      s.w1gp[fpos(tid)] = (ushort)f2bf(W1[256 * 128 + tid]);
    }
  }
  __syncthreads();

  const float b4v = b4[0];
  const int lane = tid & 63;
  const int c = lane & 15;
  const int q = lane >> 4;
  const int wgid = (int)blockIdx.x * 8 + (tid >> 6);
  const int n_tiles = (E + 63) / 64;
  const f32x4 z4 = {0.f, 0.f, 0.f, 0.f};

  bh8 w1gb[4];
#pragma unroll
  for (int kf = 0; kf < 4; ++kf)
    w1gb[kf] = *(const bh8*)&s.w1gp[kf * 32 + q * 8];

  for (int tile = wgid; tile < n_tiles; tile += NWAVES_TOTAL) {
    const int ebase = tile * 64;

    int se[4], de[4];
    float gv[4];
#pragma unroll
    for (int et = 0; et < 4; ++et) {
      int e = ebase + et * 16 + c;
      if (e >= E) e = 0;
      se[et] = __builtin_nontemporal_load(ei + e);
      de[et] = __builtin_nontemporal_load(ei + E + e);
    }
#pragma unroll
    for (int et = 0; et < 4; ++et)
      gv[et] = __builtin_nontemporal_load(graph + (size_t)se[et] * NN + de[et]);

    // ---- layer-1 replacement: bp = relu(Pa[src] + Pb[dst] + g*w1g) ----
    bh8 bp[4][4];
#pragma unroll
    for (int et = 0; et < 4; ++et) {
      const ushort* par = Pa + (size_t)se[et] * 128 + q * 8;
      const ushort* pbr = Pb + (size_t)de[et] * 128 + q * 8;
      bh8 pa8[4], pb8[4];
#pragma unroll
      for (int kf = 0; kf < 4; ++kf) {
        pa8[kf] = *(const bh8*)(par + kf * 32);
        pb8[kf] = *(const bh8*)(pbr + kf * 32);
      }
#pragma unroll
      for (int kf = 0; kf < 4; ++kf) {
        bh8 t;
#pragma unroll
        for (int i = 0; i < 8; ++i) {
          float v = bf2f(pa8[kf][i]) + bf2f(pb8[kf][i]);
          v = fmaf(gv[et], bf2f(w1gb[kf][i]), v);
          t[i] = f2bf(fmaxf(v, 0.f));
        }
        bp[et][kf] = t;
      }
    }

    // ---- layer 2 ----
    f32x4 acc[4][8];
#pragma unroll
    for (int et = 0; et < 4; ++et)
#pragma unroll
      for (int ob = 0; ob < 8; ++ob) acc[et][ob] = z4;
#pragma unroll
    for (int kf = 0; kf < 4; ++kf) {
#pragma unroll
      for (int ob = 0; ob < 8; ++ob) {
        bh8 af = *(const bh8*)&s.w2[((ob * 4 + kf) * 64 + lane) * 8];
#pragma unroll
        for (int et = 0; et < 4; ++et)
          acc[et][ob] = __builtin_amdgcn_mfma_f32_16x16x32_bf16(af, bp[et][kf], acc[et][ob], 0, 0, 0);
      }
    }
    // relu + b2 + pack
#pragma unroll
    for (int et = 0; et < 4; ++et) {
#pragma unroll
      for (int kf = 0; kf < 4; ++kf) {
        bh8 t;
#pragma unroll
        for (int half = 0; half < 2; ++half) {
          int ob = kf * 2 + half;
#pragma unroll
          for (int r = 0; r < 4; ++r) {
            int f = ob * 16 + q * 4 + r;
            float v = fmaxf(acc[et][ob][r] + s.b2[f], 0.f);
            t[half * 4 + r] = f2bf(v);
          }
        }
        bp[et][kf] = t;
      }
    }

    // ---- layer 3 ----
#pragma unroll
    for (int et = 0; et < 4; ++et)
#pragma unroll
      for (int ob = 0; ob < 8; ++ob) acc[et][ob] = z4;
#pragma unroll
    for (int kf = 0; kf < 4; ++kf) {
#pragma unroll
      for (int ob = 0; ob < 8; ++ob) {
        bh8 af = *(const bh8*)&s.w3[((ob * 4 + kf) * 64 + lane) * 8];
#pragma unroll
        for (int et = 0; et < 4; ++et)
          acc[et][ob] = __builtin_amdgcn_mfma_f32_16x16x32_bf16(af, bp[et][kf], acc[et][ob], 0, 0, 0);
      }
    }

    // ---- fused relu3 + layer 4 + sigmoid ----
    float psum[4] = {0.f, 0.f, 0.f, 0.f};
#pragma unroll
    for (int et = 0; et < 4; ++et) {
#pragma unroll
      for (int ob = 0; ob < 8; ++ob) {
#pragma unroll
        for (int r = 0; r < 4; ++r) {
          int f = ob * 16 + q * 4 + r;
          float v = fmaxf(acc[et][ob][r] + s.b3[f], 0.f);
          psum[et] += v * s.w4[f];
        }
      }
    }
#pragma unroll
    for (int et = 0; et < 4; ++et) {
      psum[et] += __shfl_xor(psum[et], 16, 64);
      psum[et] += __shfl_xor(psum[et], 32, 64);
    }
    float vsel = (q == 0) ? psum[0] : (q == 1) ? psum[1] : (q == 2) ? psum[2] : psum[3];
    float val = vsel + b4v;
    float sig = 1.0f / (1.0f + __expf(-val));
    int eout = ebase + q * 16 + c;
    if (eout < E) __builtin_nontemporal_store(sig, out + eout);
  }
}

extern "C" void kernel_launch(void* const* d_in, const int* in_sizes, int n_in,
                              void* d_out, int out_size, void* d_ws, size_t ws_size,
                              hipStream_t stream) {
  const float* z     = (const float*)d_in[0];
  const float* graph = (const float*)d_in[2];
  const int*   ei    = (const int*)d_in[3];
  const float* W1 = (const float*)d_in[4];
  const float* b1 = (const float*)d_in[5];
  const float* W2 = (const float*)d_in[6];
  const float* b2 = (const float*)d_in[7];
  const float* W3 = (const float*)d_in[8];
  const float* b3 = (const float*)d_in[9];
  const float* W4 = (const float*)d_in[10];
  const float* b4 = (const float*)d_in[11];
  int E  = in_sizes[3] / 2;
  int NN = in_sizes[0] / 128;

  ushort* Pa  = (ushort*)d_ws;
  ushort* Pb  = Pa + (size_t)NN * 128;
  ushort* w2f = Pb + (size_t)NN * 128;
  ushort* w3f = w2f + 16384;

  hipLaunchKernelGGL(precompute_p, dim3((NN + 3) / 4), dim3(256), 0, stream,
                     z, W1, b1, Pa, Pb, NN);
  hipLaunchKernelGGL(pack_w, dim3(32), dim3(512), 0, stream, W2, W3, w2f, w3f);
  hipLaunchKernelGGL(edge_mlp, dim3(NBLOCKS), dim3(512), 0, stream,
                     Pa, Pb, w2f, w3f, graph, ei, W1, b2, b3, W4, b4,
                     (float*)d_out, E, NN);
}